// Round 8
// baseline (533.182 us; speedup 1.0000x reference)
//
#include <hip/hip_runtime.h>
#include <hip/hip_bf16.h>

#define M_TOK 2048
#define KDIM 2048
#define NDIM 1408
#define NEXP 8
#define RROWS (M_TOK * 2)
#define CAP 1024

typedef __attribute__((ext_vector_type(8))) short short8;
typedef __attribute__((ext_vector_type(4))) float f32x4;

__device__ __forceinline__ unsigned short bf16rn(float f) {
    unsigned int u = __builtin_bit_cast(unsigned int, f);
    u += 0x7FFFu + ((u >> 16) & 1u);
    return (unsigned short)(u >> 16);
}
__device__ __forceinline__ unsigned int pk2(float a, float b) {
    return (unsigned int)bf16rn(a) | ((unsigned int)bf16rn(b) << 16);
}
// packed fp32x2 -> bf16x2 (RNE), compiler emits v_cvt_pk_bf16_f32
__device__ __forceinline__ unsigned int cvtpk(float a, float b) {
    __hip_bfloat162 h = __float22bfloat162_rn(make_float2(a, b));
    unsigned int u;
    __builtin_memcpy(&u, &h, 4);
    return u;
}

// async global->LDS, 16 B per lane; LDS dest wave-uniform base + lane*16
__device__ __forceinline__ void glds16(const void* g, void* l) {
    __builtin_amdgcn_global_load_lds(
        (const __attribute__((address_space(1))) unsigned int*)g,
        (__attribute__((address_space(3))) unsigned int*)l, 16, 0, 0);
}

// ---------------- routing + dispatch (fp32 -> bf16 row copy) ----------------
__global__ void k_route(const float* __restrict__ h, const int* __restrict__ idx,
                        int* __restrict__ cnt, int* __restrict__ slot_of,
                        unsigned short* __restrict__ bufA) {
    int r = blockIdx.x;
    __shared__ int s_ep;
    if (threadIdx.x == 0) {
        int e = idx[r];
        int p = atomicAdd(&cnt[e], 1);
        int ep = e * CAP + p;
        slot_of[r] = ep;
        s_ep = ep;
    }
    __syncthreads();
    int ep = s_ep;
    const float4* src = (const float4*)(h + (size_t)(r >> 1) * KDIM) + threadIdx.x * 2;
    float4 a = src[0], b = src[1];
    uint4 o;
    o.x = pk2(a.x, a.y); o.y = pk2(a.z, a.w);
    o.z = pk2(b.x, b.y); o.w = pk2(b.z, b.w);
    *((uint4*)(bufA + (size_t)ep * KDIM) + threadIdx.x) = o;
}

// ------- merged weight reorder: [E][R][C] fp32 -> [E][C/64][R][64] bf16 -----
// y selects tensor. Per lane: 8 cols (2 float4 loads, 1 uint4 store);
// 8 lanes/chunk -> 128-B write runs; reads 2 KB contiguous per wave-row.
__global__ __launch_bounds__(256)
void k_reorder3(const float* __restrict__ gw, const float* __restrict__ uw,
                const float* __restrict__ dwn,
                unsigned short* __restrict__ gwb, unsigned short* __restrict__ uwb,
                unsigned short* __restrict__ dwb) {
    const int y = blockIdx.y;
    const int t = blockIdx.x;
    int R, C, spans;
    const float* in;
    unsigned short* out;
    if (y == 2) { R = KDIM; C = NDIM; spans = 3; in = dwn; out = dwb; }
    else { R = NDIM; C = KDIM; spans = 4; in = (y ? uw : gw); out = (y ? uwb : gwb); }
    const int per_e = (R >> 6) * spans;
    if (t >= NEXP * per_e) return;
    const int e = t / per_e;
    const int rem = t % per_e;
    const int slab = rem / spans;
    const int span = rem % spans;
    const int tid = threadIdx.x;
    const int wave = tid >> 6, lane = tid & 63;
    const int c = span * 512 + lane * 8;
    if (c >= C) return;
    const int r0 = slab * 64 + wave * 16;
    const int NC = C >> 6;
    const float* src = in + ((size_t)e * R + r0) * C + c;
    unsigned short* dst = out + (((size_t)e * NC + (c >> 6)) * R + r0) * 64 + (c & 63);
#pragma unroll
    for (int i = 0; i < 16; i++) {
        float4 v0 = *(const float4*)(src + (size_t)i * C);
        float4 v1 = *(const float4*)(src + (size_t)i * C + 4);
        uint4 o;
        o.x = cvtpk(v0.x, v0.y); o.y = cvtpk(v0.z, v0.w);
        o.z = cvtpk(v1.x, v1.y); o.w = cvtpk(v1.z, v1.w);
        *(uint4*)(dst + i * 64) = o;
    }
}

// ---------------- GEMM1: g,u = A @ W^T ; h = silu(min(g,10)) * clip(u) ------
// 128x64 tile. 2-deep weight prefetch (3 buf), 1-deep A (2 buf), counted vmcnt:
// step-top outstanding = [W(k):4, A(k):4, W(k+1):4] -> vmcnt(4) drains W(k)+A(k).
__global__ __launch_bounds__(256, 2)
void k_gemm1(const unsigned short* __restrict__ bufA,
             const unsigned short* __restrict__ gwb,
             const unsigned short* __restrict__ uwb,
             const int* __restrict__ cnt, unsigned short* __restrict__ hbuf) {
    const int f = blockIdx.x;
    const int e = f & 7;             // expert -> XCD
    const int t = f >> 3;
    const int n_blk = t % 22;
    const int m_blk = t / 22;        // 0..7
    const int m0 = m_blk * 128;
    if (m0 >= cnt[e]) return;
    const int n0 = n_blk * 64;

    const unsigned short* A = bufA + (size_t)e * CAP * KDIM;
    const unsigned short* Gc = gwb + (size_t)e * 32 * NDIM * 64;
    const unsigned short* Uc = uwb + (size_t)e * 32 * NDIM * 64;

    __shared__ unsigned short sA[2][128 * 64];  // 32 KB
    __shared__ unsigned short sG[3][64 * 64];   // 24 KB
    __shared__ unsigned short sU[3][64 * 64];   // 24 KB -> 80 KB total

    const int tid = threadIdx.x;
    const int lane = tid & 63;
    const int wave = tid >> 6;
    const int wm = (wave >> 1) * 64, wn = (wave & 1) * 32;
    const int q = lane >> 4, l15 = lane & 15;
    // DMA source swizzle: lane covers (row_in_seg = lane>>3, granule (lane&7)^(row&7))
    const int sr = lane >> 3;
    const int scb = (lane & 7) ^ (sr & 7);
    const int xi = l15 & 7;                 // reader xor key
    const int cbl0 = (q ^ xi) * 8;
    const int cbl1 = ((4 + q) ^ xi) * 8;

    f32x4 accG[4][2] = {};
    f32x4 accU[4][2] = {};

#define STAGE_A1(kc, b) do {                                                            \
        _Pragma("unroll")                                                               \
        for (int c_ = 0; c_ < 4; c_++) {                                                \
            int seg = wave * 4 + c_;                                                    \
            glds16(A + (size_t)(m0 + seg * 8 + sr) * KDIM + (kc) * 64 + scb * 8,        \
                   &sA[b][seg * 512]);                                                  \
        }                                                                               \
    } while (0)
#define STAGE_W1(kc, b) do {                                                            \
        _Pragma("unroll")                                                               \
        for (int c_ = 0; c_ < 2; c_++) {                                                \
            int seg = wave * 2 + c_;                                                    \
            glds16(Gc + ((size_t)(kc) * NDIM + n0 + seg * 8 + sr) * 64 + scb * 8,       \
                   &sG[b][seg * 512]);                                                  \
            glds16(Uc + ((size_t)(kc) * NDIM + n0 + seg * 8 + sr) * 64 + scb * 8,       \
                   &sU[b][seg * 512]);                                                  \
        }                                                                               \
    } while (0)

    // prologue: A(0), W(0), W(1) in flight (12 loads/wave)
    STAGE_A1(0, 0);
    STAGE_W1(0, 0);
    STAGE_W1(1, 1);

    for (int kc = 0; kc < 32; kc++) {
        const int cur = kc & 1;
        const int wcur = kc % 3;
        if (kc == 31) {
            asm volatile("s_waitcnt vmcnt(0)" ::: "memory");   // drain all
        } else {
            asm volatile("s_waitcnt vmcnt(4)" ::: "memory");   // W(k)+A(k) done; W(k+1) flies
        }
        __builtin_amdgcn_sched_barrier(0);
        __builtin_amdgcn_s_barrier();       // all waves' DMAs for kc visible; old bufs free
        __builtin_amdgcn_sched_barrier(0);
        if (kc + 1 < 32) STAGE_A1(kc + 1, cur ^ 1);
        if (kc + 2 < 32) STAGE_W1(kc + 2, (kc + 2) % 3);

#pragma unroll
        for (int kh = 0; kh < 2; kh++) {
            const int co = kh ? cbl1 : cbl0;
            short8 af[4], gf[2], uf[2];
#pragma unroll
            for (int i = 0; i < 4; i++)
                af[i] = *(const short8*)&sA[cur][(wm + i * 16 + l15) * 64 + co];
#pragma unroll
            for (int j = 0; j < 2; j++) {
                gf[j] = *(const short8*)&sG[wcur][(wn + j * 16 + l15) * 64 + co];
                uf[j] = *(const short8*)&sU[wcur][(wn + j * 16 + l15) * 64 + co];
            }
#pragma unroll
            for (int i = 0; i < 4; i++)
#pragma unroll
                for (int j = 0; j < 2; j++) {
                    accG[i][j] = __builtin_amdgcn_mfma_f32_16x16x32_bf16(af[i], gf[j], accG[i][j], 0, 0, 0);
                    accU[i][j] = __builtin_amdgcn_mfma_f32_16x16x32_bf16(af[i], uf[j], accU[i][j], 0, 0, 0);
                }
        }
    }
#undef STAGE_A1
#undef STAGE_W1

    unsigned short* H = hbuf + (size_t)e * CAP * NDIM;
#pragma unroll
    for (int i = 0; i < 4; i++)
#pragma unroll
        for (int j = 0; j < 2; j++) {
            int col = n0 + wn + j * 16 + l15;
#pragma unroll
            for (int rg = 0; rg < 4; rg++) {
                int row = m0 + wm + i * 16 + q * 4 + rg;
                float g = accG[i][j][rg];
                float u = accU[i][j][rg];
                g = fminf(g, 10.f);
                u = fminf(fmaxf(u, -10.f), 10.f);
                float hv = g / (1.f + __expf(-g)) * u;
                H[(size_t)row * NDIM + col] = bf16rn(hv);
            }
        }
}

// ---------------- GEMM2: d = h @ dw^T -> dbuf (fp32, no atomics) ------------
// 128x64 tile, same 2-deep weight / 1-deep A counted-vmcnt pipeline (NT=22).
__global__ __launch_bounds__(256, 2)
void k_gemm2(const unsigned short* __restrict__ hbuf,
             const unsigned short* __restrict__ dwb, const int* __restrict__ cnt,
             float* __restrict__ dbuf) {
    const int f = blockIdx.x;
    const int e = f & 7;
    const int t = f >> 3;
    const int n_blk = t & 31;        // over KDIM
    const int m_blk = t >> 5;        // 0..7
    const int cnt_e = cnt[e];
    const int m0 = m_blk * 128;
    if (m0 >= cnt_e) return;
    const int n0 = n_blk * 64;

    const unsigned short* Ah = hbuf + (size_t)e * CAP * NDIM;
    const unsigned short* Dc = dwb + (size_t)e * 22 * KDIM * 64;

    __shared__ unsigned short sA[2][128 * 64];  // 32 KB
    __shared__ unsigned short sB[3][64 * 64];   // 24 KB -> 56 KB

    const int tid = threadIdx.x;
    const int lane = tid & 63;
    const int wave = tid >> 6;
    const int wm = (wave >> 1) * 64, wn = (wave & 1) * 32;
    const int q = lane >> 4, l15 = lane & 15;
    const int sr = lane >> 3;
    const int scb = (lane & 7) ^ (sr & 7);
    const int xi = l15 & 7;
    const int cbl0 = (q ^ xi) * 8;
    const int cbl1 = ((4 + q) ^ xi) * 8;

    f32x4 acc[4][2] = {};

#define STAGE_A2(nc, b) do {                                                            \
        _Pragma("unroll")                                                               \
        for (int c_ = 0; c_ < 4; c_++) {                                                \
            int seg = wave * 4 + c_;                                                    \
            glds16(Ah + (size_t)(m0 + seg * 8 + sr) * NDIM + (nc) * 64 + scb * 8,       \
                   &sA[b][seg * 512]);                                                  \
        }                                                                               \
    } while (0)
#define STAGE_W2(nc, b) do {                                                            \
        _Pragma("unroll")                                                               \
        for (int c_ = 0; c_ < 2; c_++) {                                                \
            int seg = wave * 2 + c_;                                                    \
            glds16(Dc + ((size_t)(nc) * KDIM + n0 + seg * 8 + sr) * 64 + scb * 8,       \
                   &sB[b][seg * 512]);                                                  \
        }                                                                               \
    } while (0)

    STAGE_A2(0, 0);
    STAGE_W2(0, 0);
    STAGE_W2(1, 1);

    for (int nc = 0; nc < 22; nc++) {
        const int cur = nc & 1;
        const int wcur = nc % 3;
        if (nc == 21) {
            asm volatile("s_waitcnt vmcnt(0)" ::: "memory");
        } else {
            asm volatile("s_waitcnt vmcnt(2)" ::: "memory");   // leaves W(nc+1):2 in flight
        }
        __builtin_amdgcn_sched_barrier(0);
        __builtin_amdgcn_s_barrier();
        __builtin_amdgcn_sched_barrier(0);
        if (nc + 1 < 22) STAGE_A2(nc + 1, cur ^ 1);
        if (nc + 2 < 22) STAGE_W2(nc + 2, (nc + 2) % 3);

#pragma unroll
        for (int kh = 0; kh < 2; kh++) {
            const int co = kh ? cbl1 : cbl0;
            short8 af[4], bfr[2];
#pragma unroll
            for (int i = 0; i < 4; i++)
                af[i] = *(const short8*)&sA[cur][(wm + i * 16 + l15) * 64 + co];
#pragma unroll
            for (int j = 0; j < 2; j++)
                bfr[j] = *(const short8*)&sB[wcur][(wn + j * 16 + l15) * 64 + co];
#pragma unroll
            for (int i = 0; i < 4; i++)
#pragma unroll
                for (int j = 0; j < 2; j++)
                    acc[i][j] = __builtin_amdgcn_mfma_f32_16x16x32_bf16(af[i], bfr[j], acc[i][j], 0, 0, 0);
        }
    }
#undef STAGE_A2
#undef STAGE_W2

    float* D = dbuf + (size_t)e * CAP * KDIM;
#pragma unroll
    for (int i = 0; i < 4; i++) {
#pragma unroll
        for (int rg = 0; rg < 4; rg++) {
            int row = m0 + wm + i * 16 + q * 4 + rg;
            if (row < cnt_e) {
                float* drow = D + (size_t)row * KDIM + n0 + wn + l15;
#pragma unroll
                for (int j = 0; j < 2; j++)
                    drow[j * 16] = acc[i][j][rg];
            }
        }
    }
}

// ---------------- combine: out[tok] = g0*d[slot0] + g1*d[slot1] -------------
__global__ void k_combine(const float* __restrict__ dbuf, const int* __restrict__ slot_of,
                          const float* __restrict__ gate, float* __restrict__ out) {
    int tk = blockIdx.x;
    int s0 = slot_of[2 * tk], s1 = slot_of[2 * tk + 1];
    float g0 = gate[2 * tk], g1 = gate[2 * tk + 1];
    const float4* r0 = (const float4*)(dbuf + (size_t)s0 * KDIM);
    const float4* r1 = (const float4*)(dbuf + (size_t)s1 * KDIM);
    float4* o = (float4*)(out + (size_t)tk * KDIM);
    int i = threadIdx.x * 2;
#pragma unroll
    for (int c = 0; c < 2; c++) {
        float4 a = r0[i + c], b = r1[i + c];
        float4 v;
        v.x = g0 * a.x + g1 * b.x;
        v.y = g0 * a.y + g1 * b.y;
        v.z = g0 * a.z + g1 * b.z;
        v.w = g0 * a.w + g1 * b.w;
        o[i + c] = v;
    }
}

extern "C" void kernel_launch(void* const* d_in, const int* in_sizes, int n_in,
                              void* d_out, int out_size, void* d_ws, size_t ws_size,
                              hipStream_t stream) {
    const float* flat_h = (const float*)d_in[0];
    const int* flat_idx = (const int*)d_in[1];
    const float* flat_gate = (const float*)d_in[2];
    const float* gw = (const float*)d_in[3];
    const float* uw = (const float*)d_in[4];
    const float* dwn = (const float*)d_in[5];
    float* out = (float*)d_out;

    char* w = (char*)d_ws;
    int* cnt = (int*)w;                         // 256 B
    int* slot_of = (int*)(w + 256);             // 16 KB
    unsigned short* bufA = (unsigned short*)(w + 1048576ull);     // 32 MiB
    unsigned short* hbuf = (unsigned short*)(w + 34603008ull);    // 22 MiB
    unsigned short* gwb  = (unsigned short*)(w + 57671680ull);    // 46.1 MB (chunked bf16)
    unsigned short* uwb  = (unsigned short*)(w + 103809024ull);   // 46.1 MB
    unsigned short* dwb  = (unsigned short*)(w + 149946368ull);   // 46.1 MB -> ends ~187 MiB
    float* dbuf = (float*)(w + 57671680ull);    // aliases gwb/uwb (dead after gemm1), 64 MiB

    hipMemsetAsync(cnt, 0, 256, stream);

    k_route<<<RROWS, 256, 0, stream>>>(flat_h, flat_idx, cnt, slot_of, bufA);
    k_reorder3<<<dim3(768, 3), 256, 0, stream>>>(gw, uw, dwn, gwb, uwb, dwb);
    k_gemm1<<<8 * 22 * 8, 256, 0, stream>>>(bufA, gwb, uwb, cnt, hbuf);
    k_gemm2<<<8 * 32 * 8, 256, 0, stream>>>(hbuf, dwb, cnt, dbuf);
    k_combine<<<M_TOK, 256, 0, stream>>>(dbuf, slot_of, flat_gate, out);
}